// Round 2
// baseline (423.432 us; speedup 1.0000x reference)
//
#include <hip/hip_runtime.h>
#include <hip/hip_bf16.h>

#define S_ 15
#define B_ 32
#define N_ 3000
#define FIN 16
#define RF 1000
#define GEMM_NC 8
#define NCHK 375  // N_/GEMM_NC

__device__ __forceinline__ float sigf(float x){ return 1.0f/(1.0f+expf(-x)); }

__global__ void k_zero(int* p, int n){
  int i = blockIdx.x*blockDim.x + threadIdx.x;
  if (i < n) p[i] = 0;
}

__global__ void k_count(const int* __restrict__ dst, int E, int* __restrict__ cnt){
  int e = blockIdx.x*blockDim.x + threadIdx.x;
  if (e < E) atomicAdd(&cnt[dst[e]], 1);
}

// single block of 1024: exclusive scan of cnt -> indptr, and dinv = rsqrt(cnt+1)
__global__ void k_scan(const int* __restrict__ cnt, int* __restrict__ indptr, float* __restrict__ dinv){
  __shared__ int sc[1024];
  int tid = threadIdx.x;
  int i0 = tid*3;
  int c0 = (i0+0 < N_) ? cnt[i0+0] : 0;
  int c1 = (i0+1 < N_) ? cnt[i0+1] : 0;
  int c2 = (i0+2 < N_) ? cnt[i0+2] : 0;
  int ssum = c0+c1+c2;
  sc[tid] = ssum; __syncthreads();
  for (int off=1; off<1024; off<<=1){
    int add = (tid>=off) ? sc[tid-off] : 0;
    __syncthreads();
    sc[tid] += add;
    __syncthreads();
  }
  int excl = sc[tid]-ssum;
  if (i0+0 < N_){ indptr[i0+0]=excl;       dinv[i0+0]=rsqrtf((float)(c0+1)); }
  if (i0+1 < N_){ indptr[i0+1]=excl+c0;    dinv[i0+1]=rsqrtf((float)(c1+1)); }
  if (i0+2 < N_){ indptr[i0+2]=excl+c0+c1; dinv[i0+2]=rsqrtf((float)(c2+1)); }
  if (tid==1023) indptr[N_] = sc[1023];
}

__global__ void k_fill(const int* __restrict__ src, const int* __restrict__ dst, int E,
                       const int* __restrict__ indptr, int* __restrict__ cursor,
                       const float* __restrict__ dinv, int* __restrict__ col, float* __restrict__ wgt){
  int e = blockIdx.x*blockDim.x + threadIdx.x;
  if (e < E){
    int d = dst[e], s = src[e];
    int pos = indptr[d] + atomicAdd(&cursor[d], 1);
    col[pos] = s;
    wgt[pos] = dinv[s]*dinv[d];
  }
}

// t1[s][n][b] = float2( x[s,b,n,:]@W1[s,:,0]+b1[s,0], ...@W1[s,:,1]+b1[s,1] )
__global__ void k_t1(const float* __restrict__ x, const float* __restrict__ W1,
                     const float* __restrict__ b1, float2* __restrict__ t1){
  int idx = blockIdx.x*256 + threadIdx.x;
  if (idx >= S_*N_*B_) return;
  int b = idx & 31;
  int n = (idx >> 5) % N_;
  int s = idx / (N_*B_);
  const float4* xp = (const float4*)(x + ((size_t)(s*B_+b)*N_ + n)*FIN);
  float4 x0 = xp[0], x1 = xp[1], x2 = xp[2], x3 = xp[3];
  float xv[16] = {x0.x,x0.y,x0.z,x0.w, x1.x,x1.y,x1.z,x1.w,
                  x2.x,x2.y,x2.z,x2.w, x3.x,x3.y,x3.z,x3.w};
  const float* w = W1 + s*FIN*2;
  float a0 = b1[s*2+0], a1 = b1[s*2+1];
  #pragma unroll
  for (int f=0; f<16; ++f){ a0 += xv[f]*w[f*2+0]; a1 += xv[f]*w[f*2+1]; }
  t1[(size_t)(s*N_+n)*32 + b] = make_float2(a0, a1);
}

// edge-sum over t1 (2ch) + sigmoid + conv2 transform -> t2[s][n][b]
__global__ void k_conv1(const float* __restrict__ t1, const int* __restrict__ indptr,
                        const int* __restrict__ col, const float* __restrict__ wgt,
                        const float* __restrict__ dinv, const float* __restrict__ W2,
                        const float* __restrict__ b2, float* __restrict__ t2){
  int s = blockIdx.y;
  int wv = threadIdx.x >> 6, lane = threadIdx.x & 63;
  int bb = lane >> 1, k = lane & 1;
  float w20 = W2[s*2+0], w21 = W2[s*2+1], bias2 = b2[s];
  const float* tbase = t1 + (size_t)s*N_*64;
  int d0 = blockIdx.x*64 + wv*16;
  for (int i=0; i<16; ++i){
    int d = d0 + i;
    if (d >= N_) break;   // uniform per wave
    int ip0 = indptr[d], ip1 = indptr[d+1];
    float di = dinv[d];
    float acc = tbase[(size_t)d*64 + lane] * (di*di);
    for (int e=ip0; e<ip1; ++e){
      int c = col[e]; float wt = wgt[e];
      acc += wt * tbase[(size_t)c*64 + lane];
    }
    float gk = sigf(acc);
    float other = __shfl_xor(gk, 1);
    if (k == 0) t2[(size_t)(s*N_+d)*32 + bb] = gk*w20 + other*w21 + bias2;
  }
}

// edge-sum over t2 (1ch) + sigmoid -> g[s][n][b]
__global__ void k_conv2(const float* __restrict__ t2, const int* __restrict__ indptr,
                        const int* __restrict__ col, const float* __restrict__ wgt,
                        const float* __restrict__ dinv, float* __restrict__ g){
  int s = blockIdx.y;
  int wv = threadIdx.x >> 6, lane = threadIdx.x & 63;
  int half = lane >> 5, bb = lane & 31;
  const float* tbase = t2 + (size_t)s*N_*32;
  int d0 = blockIdx.x*64 + wv*16;
  for (int i=0; i<8; ++i){
    int d = d0 + i*2 + half;
    if (d < N_){
      int ip0 = indptr[d], ip1 = indptr[d+1];
      float di = dinv[d];
      float acc = tbase[(size_t)d*32 + bb] * (di*di);
      for (int e=ip0; e<ip1; ++e) acc += wgt[e] * tbase[(size_t)col[e]*32 + bb];
      g[(size_t)(s*N_+d)*32 + bb] = sigf(acc);
    }
  }
}

// y_partial[c][s][b][r] = sum_{n in chunk c} g[s,n,b]*lin_W[s,n,r]
__global__ __launch_bounds__(256) void k_gemm(const float* __restrict__ g,
                                              const float* __restrict__ W,
                                              float* __restrict__ partial){
  __shared__ float gs[NCHK*32];
  int s = blockIdx.z, c = blockIdx.y, r0 = blockIdx.x*256;
  int tid = threadIdx.x;
  const float* gsrc = g + (size_t)(s*N_ + c*NCHK)*32;
  for (int i=tid; i<NCHK*32; i+=256) gs[i] = gsrc[i];
  __syncthreads();
  int r = r0 + tid;
  bool act = r < RF;
  float acc[32];
  #pragma unroll
  for (int i=0; i<32; ++i) acc[i] = 0.f;
  const float* wp = W + (size_t)(s*N_ + c*NCHK)*RF + r;
  for (int n=0; n<NCHK; ++n){
    float wvv = act ? wp[(size_t)n*RF] : 0.f;
    const float4* g4 = (const float4*)(gs + n*32);
    #pragma unroll
    for (int q=0; q<8; ++q){
      float4 gv = g4[q];
      acc[q*4+0] += gv.x*wvv; acc[q*4+1] += gv.y*wvv;
      acc[q*4+2] += gv.z*wvv; acc[q*4+3] += gv.w*wvv;
    }
  }
  if (act){
    #pragma unroll
    for (int b=0; b<32; ++b)
      partial[(size_t)c*(S_*B_*RF) + (size_t)(s*32+b)*RF + r] = acc[b];
  }
}

__global__ void k_reduce(const float* __restrict__ partial, float* __restrict__ y){
  int i = blockIdx.x*256 + threadIdx.x;
  if (i < S_*B_*RF){
    float s = 0.f;
    #pragma unroll
    for (int c=0; c<GEMM_NC; ++c) s += partial[(size_t)c*(S_*B_*RF) + i];
    y[i] = s;
  }
}

// BatchNorm over b (in place): thread per (s,r), 32 values in regs
__global__ void k_bn(float* __restrict__ y, const float* __restrict__ gamma,
                     const float* __restrict__ beta){
  int idx = blockIdx.x*256 + threadIdx.x;
  if (idx >= S_*RF) return;
  int s = idx / RF, r = idx % RF;
  float v[32]; float mu = 0.f;
  #pragma unroll
  for (int b=0; b<32; ++b){ v[b] = y[(size_t)(s*32+b)*RF + r]; mu += v[b]; }
  mu *= (1.f/32.f);
  float var = 0.f;
  #pragma unroll
  for (int b=0; b<32; ++b){ float d = v[b]-mu; var += d*d; }
  var *= (1.f/32.f);
  float sc = gamma[idx]*rsqrtf(var + 1e-5f);
  float sh = beta[idx] - mu*sc;
  #pragma unroll
  for (int b=0; b<32; ++b) y[(size_t)(s*32+b)*RF + r] = v[b]*sc + sh;
}

// gi0[s,b,:] = y[s,b,:]@Wih0^T + bih0  (one wave per (s,b))
__global__ void k_gi0(const float* __restrict__ y, const float* __restrict__ Wih0,
                      const float* __restrict__ bih0, float* __restrict__ gi0){
  int sb = blockIdx.x;
  int lane = threadIdx.x;
  const float* yb = y + (size_t)sb*RF;
  float a[9];
  #pragma unroll
  for (int j=0; j<9; ++j) a[j] = 0.f;
  for (int r=lane; r<RF; r+=64){
    float yv = yb[r];
    #pragma unroll
    for (int j=0; j<9; ++j) a[j] += yv*Wih0[j*RF + r];
  }
  #pragma unroll
  for (int j=0; j<9; ++j){
    #pragma unroll
    for (int off=32; off>=1; off>>=1) a[j] += __shfl_down(a[j], off);
  }
  if (lane == 0){
    #pragma unroll
    for (int j=0; j<9; ++j) gi0[sb*9 + j] = a[j] + bih0[j];
  }
}

// sequential 2-layer GRU + decoder; one block, lane = batch element.
// OUTPUT IS FLOAT32 (reference returns f32; round-1 wrote bf16 -> dtype mismatch).
__global__ void k_gru(const float* __restrict__ gi0, const float* __restrict__ Whh0,
                      const float* __restrict__ bhh0, const float* __restrict__ Wih1,
                      const float* __restrict__ Whh1, const float* __restrict__ bih1,
                      const float* __restrict__ bhh1, const float* __restrict__ dW,
                      const float* __restrict__ db, float* __restrict__ out){
  int b = threadIdx.x;
  if (b >= 32) return;
  float whh0[27], wih1[27], whh1[27], bh0[9], bi1[9], bh1[9];
  #pragma unroll
  for (int i=0; i<27; ++i){ whh0[i]=Whh0[i]; wih1[i]=Wih1[i]; whh1[i]=Whh1[i]; }
  #pragma unroll
  for (int i=0; i<9; ++i){ bh0[i]=bhh0[i]; bi1[i]=bih1[i]; bh1[i]=bhh1[i]; }
  float dw0=dW[0], dw1=dW[1], dw2=dW[2], db0=db[0];
  float h0[3]={0,0,0}, h1[3]={0,0,0}, nh[3];
  for (int t=0; t<S_; ++t){
    const float* gi = gi0 + (size_t)(t*32+b)*9;
    float gh[9];
    #pragma unroll
    for (int j=0; j<9; ++j)
      gh[j] = bh0[j] + whh0[j*3+0]*h0[0] + whh0[j*3+1]*h0[1] + whh0[j*3+2]*h0[2];
    #pragma unroll
    for (int k=0; k<3; ++k){
      float r = sigf(gi[k]+gh[k]);
      float z = sigf(gi[3+k]+gh[3+k]);
      float nn = tanhf(gi[6+k] + r*gh[6+k]);
      nh[k] = (1.f-z)*nn + z*h0[k];
    }
    h0[0]=nh[0]; h0[1]=nh[1]; h0[2]=nh[2];
    float gi1[9], gh1[9];
    #pragma unroll
    for (int j=0; j<9; ++j){
      gi1[j] = bi1[j] + wih1[j*3+0]*h0[0] + wih1[j*3+1]*h0[1] + wih1[j*3+2]*h0[2];
      gh1[j] = bh1[j] + whh1[j*3+0]*h1[0] + whh1[j*3+1]*h1[1] + whh1[j*3+2]*h1[2];
    }
    #pragma unroll
    for (int k=0; k<3; ++k){
      float r = sigf(gi1[k]+gh1[k]);
      float z = sigf(gi1[3+k]+gh1[3+k]);
      float nn = tanhf(gi1[6+k] + r*gh1[6+k]);
      nh[k] = (1.f-z)*nn + z*h1[k];
    }
    h1[0]=nh[0]; h1[1]=nh[1]; h1[2]=nh[2];
    float o = dw0*h1[0] + dw1*h1[1] + dw2*h1[2] + db0;
    out[t*32 + b] = o;
  }
  #pragma unroll
  for (int j=0; j<3; ++j){
    out[S_*B_ + b*3 + j]        = h0[j];   // hn layer 0
    out[S_*B_ + 96 + b*3 + j]   = h1[j];   // hn layer 1
  }
}

extern "C" void kernel_launch(void* const* d_in, const int* in_sizes, int n_in,
                              void* d_out, int out_size, void* d_ws, size_t ws_size,
                              hipStream_t stream) {
  const float* x    = (const float*)d_in[0];
  const int*   ei   = (const int*)d_in[1];
  int E = in_sizes[1] / 2;
  const float* c1W  = (const float*)d_in[2];
  const float* c1b  = (const float*)d_in[3];
  const float* c2W  = (const float*)d_in[4];
  const float* c2b  = (const float*)d_in[5];
  const float* linW = (const float*)d_in[6];
  // d_in[7] = lin_b: cancels exactly in BatchNorm (y - mean), skipped
  const float* gma  = (const float*)d_in[8];
  const float* bta  = (const float*)d_in[9];
  const float* Wih0 = (const float*)d_in[10];
  const float* Whh0 = (const float*)d_in[11];
  const float* bih0 = (const float*)d_in[12];
  const float* bhh0 = (const float*)d_in[13];
  const float* Wih1 = (const float*)d_in[14];
  const float* Whh1 = (const float*)d_in[15];
  const float* bih1 = (const float*)d_in[16];
  const float* bhh1 = (const float*)d_in[17];
  const float* dW   = (const float*)d_in[18];
  const float* db   = (const float*)d_in[19];

  char* ws = (char*)d_ws;
  size_t off = 0;
  auto take = [&](size_t bytes)->char* {
    char* p = ws + off;
    off = (off + bytes + 255) & ~(size_t)255;
    return p;
  };
  // small CSR + misc block (~0.45 MB)
  int*    cnt     = (int*)take(N_*4);
  int*    indptr  = (int*)take((N_+1)*4);
  int*    cursor  = (int*)take(N_*4);
  float*  dinv    = (float*)take(N_*4);
  int*    col     = (int*)take((size_t)E*4);
  float*  wgt     = (float*)take((size_t)E*4);
  float*  gi0     = (float*)take((size_t)S_*B_*9*4);
  // large blocks with lifetime-based aliasing:
  //   t1 (11.52MB) live: k_t1 -> k_conv1
  //   t2 ( 5.76MB) live: k_conv1 -> k_conv2
  //   g  ( 5.76MB) live: k_conv2 -> k_gemm
  //   partial (15.36MB) live: k_gemm -> k_reduce   [aliases t1+t2, both dead]
  //   y  ( 1.92MB) live: k_reduce -> k_gi0
  char* bigbase = take((size_t)S_*N_*B_*8);          // t1 region
  char* t2base  = take((size_t)S_*N_*B_*4);          // t2 region
  float2* t1    = (float2*)bigbase;
  float*  t2    = (float*)t2base;
  float*  partial = (float*)bigbase;                 // 15.36MB <= 17.28MB (t1+t2)
  float*  g     = (float*)take((size_t)S_*N_*B_*4);
  float*  y     = (float*)take((size_t)S_*B_*RF*4);

  const int* esrc = ei;
  const int* edst = ei + E;

  k_zero<<<(N_+255)/256, 256, 0, stream>>>(cnt, N_);
  k_zero<<<(N_+255)/256, 256, 0, stream>>>(cursor, N_);
  k_count<<<(E+255)/256, 256, 0, stream>>>(edst, E, cnt);
  k_scan<<<1, 1024, 0, stream>>>(cnt, indptr, dinv);
  k_fill<<<(E+255)/256, 256, 0, stream>>>(esrc, edst, E, indptr, cursor, dinv, col, wgt);
  k_t1<<<(S_*N_*B_+255)/256, 256, 0, stream>>>(x, c1W, c1b, t1);
  k_conv1<<<dim3((N_+63)/64, S_), 256, 0, stream>>>((const float*)t1, indptr, col, wgt, dinv, c2W, c2b, t2);
  k_conv2<<<dim3((N_+63)/64, S_), 256, 0, stream>>>(t2, indptr, col, wgt, dinv, g);
  k_gemm<<<dim3(4, GEMM_NC, S_), 256, 0, stream>>>(g, linW, partial);
  k_reduce<<<(S_*B_*RF+255)/256, 256, 0, stream>>>(partial, y);
  k_bn<<<(S_*RF+255)/256, 256, 0, stream>>>(y, gma, bta);
  k_gi0<<<S_*B_, 64, 0, stream>>>(y, Wih0, bih0, gi0);
  k_gru<<<1, 64, 0, stream>>>(gi0, Whh0, bhh0, Wih1, Whh1, bih1, bhh1, dW, db,
                              (float*)d_out);
}

// Round 4
// 295.586 us; speedup vs baseline: 1.4325x; 1.4325x over previous
//
#include <hip/hip_runtime.h>
#include <hip/hip_bf16.h>

#define S_ 15
#define B_ 32
#define N_ 3000
#define FIN 16
#define RF 1000
#define GEMM_NC 8
#define NCHK 375  // N_/GEMM_NC

__device__ __forceinline__ float sigf(float x){ return 1.0f/(1.0f+expf(-x)); }

__global__ void k_zero(int* p, int n){
  int i = blockIdx.x*blockDim.x + threadIdx.x;
  if (i < n) p[i] = 0;
}

__global__ void k_count(const int* __restrict__ dst, int E, int* __restrict__ cnt){
  int e = blockIdx.x*blockDim.x + threadIdx.x;
  if (e < E) atomicAdd(&cnt[dst[e]], 1);
}

// single block of 1024: exclusive scan of cnt -> indptr, and dinv = rsqrt(cnt+1)
__global__ void k_scan(const int* __restrict__ cnt, int* __restrict__ indptr, float* __restrict__ dinv){
  __shared__ int sc[1024];
  int tid = threadIdx.x;
  int i0 = tid*3;
  int c0 = (i0+0 < N_) ? cnt[i0+0] : 0;
  int c1 = (i0+1 < N_) ? cnt[i0+1] : 0;
  int c2 = (i0+2 < N_) ? cnt[i0+2] : 0;
  int ssum = c0+c1+c2;
  sc[tid] = ssum; __syncthreads();
  for (int off=1; off<1024; off<<=1){
    int add = (tid>=off) ? sc[tid-off] : 0;
    __syncthreads();
    sc[tid] += add;
    __syncthreads();
  }
  int excl = sc[tid]-ssum;
  if (i0+0 < N_){ indptr[i0+0]=excl;       dinv[i0+0]=rsqrtf((float)(c0+1)); }
  if (i0+1 < N_){ indptr[i0+1]=excl+c0;    dinv[i0+1]=rsqrtf((float)(c1+1)); }
  if (i0+2 < N_){ indptr[i0+2]=excl+c0+c1; dinv[i0+2]=rsqrtf((float)(c2+1)); }
  if (tid==1023) indptr[N_] = sc[1023];
}

__global__ void k_fill(const int* __restrict__ src, const int* __restrict__ dst, int E,
                       const int* __restrict__ indptr, int* __restrict__ cursor,
                       const float* __restrict__ dinv, int* __restrict__ col, float* __restrict__ wgt){
  int e = blockIdx.x*blockDim.x + threadIdx.x;
  if (e < E){
    int d = dst[e], s = src[e];
    int pos = indptr[d] + atomicAdd(&cursor[d], 1);
    col[pos] = s;
    wgt[pos] = dinv[s]*dinv[d];
  }
}

// t1[s][n][b*2+k] = x[s,b,n,:]@W1[s,:,k] + b1[s,k]
__global__ void k_t1(const float* __restrict__ x, const float* __restrict__ W1,
                     const float* __restrict__ b1, float2* __restrict__ t1){
  int idx = blockIdx.x*256 + threadIdx.x;
  if (idx >= S_*N_*B_) return;
  int b = idx & 31;
  int n = (idx >> 5) % N_;
  int s = idx / (N_*B_);
  const float4* xp = (const float4*)(x + ((size_t)(s*B_+b)*N_ + n)*FIN);
  float4 x0 = xp[0], x1 = xp[1], x2 = xp[2], x3 = xp[3];
  float xv[16] = {x0.x,x0.y,x0.z,x0.w, x1.x,x1.y,x1.z,x1.w,
                  x2.x,x2.y,x2.z,x2.w, x3.x,x3.y,x3.z,x3.w};
  const float* w = W1 + s*FIN*2;
  float a0 = b1[s*2+0], a1 = b1[s*2+1];
  #pragma unroll
  for (int f=0; f<16; ++f){ a0 += xv[f]*w[f*2+0]; a1 += xv[f]*w[f*2+1]; }
  t1[(size_t)(s*N_+n)*32 + b] = make_float2(a0, a1);
}

// ROUND-2 per-node math, remapped: 2 dst nodes per WAVE (was 16).
// 22500 waves -> occupancy ~full; serial dependent-gather chain 272 -> ~34.
__global__ void k_conv1(const float* __restrict__ t1, const int* __restrict__ indptr,
                        const int* __restrict__ col, const float* __restrict__ wgt,
                        const float* __restrict__ dinv, const float* __restrict__ W2,
                        const float* __restrict__ b2, float* __restrict__ t2){
  int s = blockIdx.y;
  int wv = threadIdx.x >> 6, lane = threadIdx.x & 63;
  int bb = lane >> 1, k = lane & 1;
  float w20 = W2[s*2+0], w21 = W2[s*2+1], bias2 = b2[s];
  const float* tbase = t1 + (size_t)s*N_*64;
  int d0 = (blockIdx.x*4 + wv)*2;
  for (int i=0; i<2; ++i){
    int d = d0 + i;
    if (d >= N_) break;   // uniform per wave
    int ip0 = indptr[d], ip1 = indptr[d+1];
    float di = dinv[d];
    float acc = tbase[(size_t)d*64 + lane] * (di*di);
    for (int e=ip0; e<ip1; ++e){
      int c = col[e]; float wt = wgt[e];
      acc += wt * tbase[(size_t)c*64 + lane];
    }
    float gk = sigf(acc);
    float other = __shfl_xor(gk, 1);
    if (k == 0) t2[(size_t)(s*N_+d)*32 + bb] = gk*w20 + other*w21 + bias2;
  }
}

// ROUND-2 per-node math, remapped: 2 dst nodes per WAVE (lane halves = 2 nodes).
__global__ void k_conv2(const float* __restrict__ t2, const int* __restrict__ indptr,
                        const int* __restrict__ col, const float* __restrict__ wgt,
                        const float* __restrict__ dinv, float* __restrict__ g){
  int s = blockIdx.y;
  int wv = threadIdx.x >> 6, lane = threadIdx.x & 63;
  int half = lane >> 5, bb = lane & 31;
  const float* tbase = t2 + (size_t)s*N_*32;
  int d = (blockIdx.x*4 + wv)*2 + half;
  if (d < N_){
    int ip0 = indptr[d], ip1 = indptr[d+1];
    float di = dinv[d];
    float acc = tbase[(size_t)d*32 + bb] * (di*di);
    for (int e=ip0; e<ip1; ++e) acc += wgt[e] * tbase[(size_t)col[e]*32 + bb];
    g[(size_t)(s*N_+d)*32 + bb] = sigf(acc);
  }
}

// y_partial[c][s][b][r] = sum_{n in chunk c} g[s,n,b]*lin_W[s,n,r]
__global__ __launch_bounds__(256) void k_gemm(const float* __restrict__ g,
                                              const float* __restrict__ W,
                                              float* __restrict__ partial){
  __shared__ float gs[NCHK*32];
  int s = blockIdx.z, c = blockIdx.y, r0 = blockIdx.x*256;
  int tid = threadIdx.x;
  const float* gsrc = g + (size_t)(s*N_ + c*NCHK)*32;
  for (int i=tid; i<NCHK*32; i+=256) gs[i] = gsrc[i];
  __syncthreads();
  int r = r0 + tid;
  bool act = r < RF;
  float acc[32];
  #pragma unroll
  for (int i=0; i<32; ++i) acc[i] = 0.f;
  const float* wp = W + (size_t)(s*N_ + c*NCHK)*RF + r;
  for (int n=0; n<NCHK; ++n){
    float wvv = act ? wp[(size_t)n*RF] : 0.f;
    const float4* g4 = (const float4*)(gs + n*32);
    #pragma unroll
    for (int q=0; q<8; ++q){
      float4 gv = g4[q];
      acc[q*4+0] += gv.x*wvv; acc[q*4+1] += gv.y*wvv;
      acc[q*4+2] += gv.z*wvv; acc[q*4+3] += gv.w*wvv;
    }
  }
  if (act){
    #pragma unroll
    for (int b=0; b<32; ++b)
      partial[(size_t)c*(S_*B_*RF) + (size_t)(s*32+b)*RF + r] = acc[b];
  }
}

__global__ void k_reduce(const float* __restrict__ partial, float* __restrict__ y){
  int i = blockIdx.x*256 + threadIdx.x;
  if (i < S_*B_*RF){
    float s = 0.f;
    #pragma unroll
    for (int c=0; c<GEMM_NC; ++c) s += partial[(size_t)c*(S_*B_*RF) + i];
    y[i] = s;
  }
}

// BatchNorm over b (in place): thread per (s,r), 32 values in regs
__global__ void k_bn(float* __restrict__ y, const float* __restrict__ gamma,
                     const float* __restrict__ beta){
  int idx = blockIdx.x*256 + threadIdx.x;
  if (idx >= S_*RF) return;
  int s = idx / RF, r = idx % RF;
  float v[32]; float mu = 0.f;
  #pragma unroll
  for (int b=0; b<32; ++b){ v[b] = y[(size_t)(s*32+b)*RF + r]; mu += v[b]; }
  mu *= (1.f/32.f);
  float var = 0.f;
  #pragma unroll
  for (int b=0; b<32; ++b){ float d = v[b]-mu; var += d*d; }
  var *= (1.f/32.f);
  float sc = gamma[idx]*rsqrtf(var + 1e-5f);
  float sh = beta[idx] - mu*sc;
  #pragma unroll
  for (int b=0; b<32; ++b) y[(size_t)(s*32+b)*RF + r] = v[b]*sc + sh;
}

// gi0[s,b,:] = y[s,b,:]@Wih0^T + bih0  (one wave per (s,b))
__global__ void k_gi0(const float* __restrict__ y, const float* __restrict__ Wih0,
                      const float* __restrict__ bih0, float* __restrict__ gi0){
  int sb = blockIdx.x;
  int lane = threadIdx.x;
  const float* yb = y + (size_t)sb*RF;
  float a[9];
  #pragma unroll
  for (int j=0; j<9; ++j) a[j] = 0.f;
  for (int r=lane; r<RF; r+=64){
    float yv = yb[r];
    #pragma unroll
    for (int j=0; j<9; ++j) a[j] += yv*Wih0[j*RF + r];
  }
  #pragma unroll
  for (int j=0; j<9; ++j){
    #pragma unroll
    for (int off=32; off>=1; off>>=1) a[j] += __shfl_down(a[j], off);
  }
  if (lane == 0){
    #pragma unroll
    for (int j=0; j<9; ++j) gi0[sb*9 + j] = a[j] + bih0[j];
  }
}

// sequential 2-layer GRU + decoder; one block, lane = batch element. f32 output.
__global__ void k_gru(const float* __restrict__ gi0, const float* __restrict__ Whh0,
                      const float* __restrict__ bhh0, const float* __restrict__ Wih1,
                      const float* __restrict__ Whh1, const float* __restrict__ bih1,
                      const float* __restrict__ bhh1, const float* __restrict__ dW,
                      const float* __restrict__ db, float* __restrict__ out){
  int b = threadIdx.x;
  if (b >= 32) return;
  float whh0[27], wih1[27], whh1[27], bh0[9], bi1[9], bh1[9];
  #pragma unroll
  for (int i=0; i<27; ++i){ whh0[i]=Whh0[i]; wih1[i]=Wih1[i]; whh1[i]=Whh1[i]; }
  #pragma unroll
  for (int i=0; i<9; ++i){ bh0[i]=bhh0[i]; bi1[i]=bih1[i]; bh1[i]=bhh1[i]; }
  float dw0=dW[0], dw1=dW[1], dw2=dW[2], db0=db[0];
  float h0[3]={0,0,0}, h1[3]={0,0,0}, nh[3];
  for (int t=0; t<S_; ++t){
    const float* gi = gi0 + (size_t)(t*32+b)*9;
    float gh[9];
    #pragma unroll
    for (int j=0; j<9; ++j)
      gh[j] = bh0[j] + whh0[j*3+0]*h0[0] + whh0[j*3+1]*h0[1] + whh0[j*3+2]*h0[2];
    #pragma unroll
    for (int k=0; k<3; ++k){
      float r = sigf(gi[k]+gh[k]);
      float z = sigf(gi[3+k]+gh[3+k]);
      float nn = tanhf(gi[6+k] + r*gh[6+k]);
      nh[k] = (1.f-z)*nn + z*h0[k];
    }
    h0[0]=nh[0]; h0[1]=nh[1]; h0[2]=nh[2];
    float gi1[9], gh1[9];
    #pragma unroll
    for (int j=0; j<9; ++j){
      gi1[j] = bi1[j] + wih1[j*3+0]*h0[0] + wih1[j*3+1]*h0[1] + wih1[j*3+2]*h0[2];
      gh1[j] = bh1[j] + whh1[j*3+0]*h1[0] + whh1[j*3+1]*h1[1] + whh1[j*3+2]*h1[2];
    }
    #pragma unroll
    for (int k=0; k<3; ++k){
      float r = sigf(gi1[k]+gh1[k]);
      float z = sigf(gi1[3+k]+gh1[3+k]);
      float nn = tanhf(gi1[6+k] + r*gh1[6+k]);
      nh[k] = (1.f-z)*nn + z*h1[k];
    }
    h1[0]=nh[0]; h1[1]=nh[1]; h1[2]=nh[2];
    float o = dw0*h1[0] + dw1*h1[1] + dw2*h1[2] + db0;
    out[t*32 + b] = o;
  }
  #pragma unroll
  for (int j=0; j<3; ++j){
    out[S_*B_ + b*3 + j]        = h0[j];   // hn layer 0
    out[S_*B_ + 96 + b*3 + j]   = h1[j];   // hn layer 1
  }
}

extern "C" void kernel_launch(void* const* d_in, const int* in_sizes, int n_in,
                              void* d_out, int out_size, void* d_ws, size_t ws_size,
                              hipStream_t stream) {
  const float* x    = (const float*)d_in[0];
  const int*   ei   = (const int*)d_in[1];
  int E = in_sizes[1] / 2;
  const float* c1W  = (const float*)d_in[2];
  const float* c1b  = (const float*)d_in[3];
  const float* c2W  = (const float*)d_in[4];
  const float* c2b  = (const float*)d_in[5];
  const float* linW = (const float*)d_in[6];
  // d_in[7] = lin_b: cancels exactly in BatchNorm (y - mean), skipped
  const float* gma  = (const float*)d_in[8];
  const float* bta  = (const float*)d_in[9];
  const float* Wih0 = (const float*)d_in[10];
  const float* Whh0 = (const float*)d_in[11];
  const float* bih0 = (const float*)d_in[12];
  const float* bhh0 = (const float*)d_in[13];
  const float* Wih1 = (const float*)d_in[14];
  const float* Whh1 = (const float*)d_in[15];
  const float* bih1 = (const float*)d_in[16];
  const float* bhh1 = (const float*)d_in[17];
  const float* dW   = (const float*)d_in[18];
  const float* db   = (const float*)d_in[19];

  char* ws = (char*)d_ws;
  size_t off = 0;
  auto take = [&](size_t bytes)->char* {
    char* p = ws + off;
    off = (off + bytes + 255) & ~(size_t)255;
    return p;
  };
  // small CSR + misc block (~0.45 MB)
  int*    cnt     = (int*)take(N_*4);
  int*    indptr  = (int*)take((N_+1)*4);
  int*    cursor  = (int*)take(N_*4);
  float*  dinv    = (float*)take(N_*4);
  int*    col     = (int*)take((size_t)E*4);
  float*  wgt     = (float*)take((size_t)E*4);
  float*  gi0     = (float*)take((size_t)S_*B_*9*4);
  // large blocks with lifetime-based aliasing:
  //   t1 (11.52MB) live: k_t1 -> k_conv1
  //   t2 ( 5.76MB) live: k_conv1 -> k_conv2
  //   g  ( 5.76MB) live: k_conv2 -> k_gemm
  //   partial (15.36MB) live: k_gemm -> k_reduce   [aliases t1+t2, both dead]
  //   y  ( 1.92MB) live: k_reduce -> k_gi0
  char* bigbase = take((size_t)S_*N_*B_*8);          // t1 region
  char* t2base  = take((size_t)S_*N_*B_*4);          // t2 region
  float2* t1    = (float2*)bigbase;
  float*  t2    = (float*)t2base;
  float*  partial = (float*)bigbase;                 // 15.36MB <= 17.28MB (t1+t2)
  float*  g     = (float*)take((size_t)S_*N_*B_*4);
  float*  y     = (float*)take((size_t)S_*B_*RF*4);

  const int* esrc = ei;
  const int* edst = ei + E;

  k_zero<<<(N_+255)/256, 256, 0, stream>>>(cnt, N_);
  k_zero<<<(N_+255)/256, 256, 0, stream>>>(cursor, N_);
  k_count<<<(E+255)/256, 256, 0, stream>>>(edst, E, cnt);
  k_scan<<<1, 1024, 0, stream>>>(cnt, indptr, dinv);
  k_fill<<<(E+255)/256, 256, 0, stream>>>(esrc, edst, E, indptr, cursor, dinv, col, wgt);
  k_t1<<<(S_*N_*B_+255)/256, 256, 0, stream>>>(x, c1W, c1b, t1);
  k_conv1<<<dim3((N_+7)/8, S_), 256, 0, stream>>>((const float*)t1, indptr, col, wgt, dinv, c2W, c2b, t2);
  k_conv2<<<dim3((N_+7)/8, S_), 256, 0, stream>>>(t2, indptr, col, wgt, dinv, g);
  k_gemm<<<dim3(4, GEMM_NC, S_), 256, 0, stream>>>(g, linW, partial);
  k_reduce<<<(S_*B_*RF+255)/256, 256, 0, stream>>>(partial, y);
  k_bn<<<(S_*RF+255)/256, 256, 0, stream>>>(y, gma, bta);
  k_gi0<<<S_*B_, 64, 0, stream>>>(y, Wih0, bih0, gi0);
  k_gru<<<1, 64, 0, stream>>>(gi0, Whh0, bhh0, Wih1, Whh1, bih1, bhh1, dW, db,
                              (float*)d_out);
}